// Round 13
// baseline (515.534 us; speedup 1.0000x reference)
//
#include <hip/hip_runtime.h>
#include <hip/hip_cooperative_groups.h>

namespace cg = cooperative_groups;

// DiffusionMLS: out[row[e]] += w[e]*(u[col[e]] - u[row[e]]), F=32 fp32.
// Round 13: ONE cooperative mega-kernel (grid.sync between phases) fusing
// convert+hist -> scan -> chunk-multisplit fill -> per-segment sort+accумulate.
// Phase logic = r12; removes ~5 kernel launch/drain boundaries (~70us gap).

#define NFEAT 32
#define BUCKET_BITS 7
#define HB 128               // nodes per segment; rowLow fits 7 bits
#define MAXNB 1024           // scan/fill cell count (NBH <= 1023)
#define CH 2048              // edges per fill chunk
#define HCAP 2560            // node-phase LDS staging cap

typedef float nfloat4 __attribute__((ext_vector_type(4)));
typedef unsigned int nuint2 __attribute__((ext_vector_type(2)));

__device__ __forceinline__ float4 nt_load_f4(const float4* p) {
    nfloat4 v = __builtin_nontemporal_load((const nfloat4*)p);
    return make_float4(v.x, v.y, v.z, v.w);
}
__device__ __forceinline__ void nt_store_f4(float4* p, float4 v) {
    nfloat4 t = {v.x, v.y, v.z, v.w};
    __builtin_nontemporal_store(t, (nfloat4*)p);
}
__device__ __forceinline__ uint2 nt_load_u2(const uint2* p) {
    nuint2 v = __builtin_nontemporal_load((const nuint2*)p);
    uint2 r; r.x = v.x; r.y = v.y; return r;
}

struct FillSh {
    int hist[MAXNB];
    int sc[MAXNB];
    int gb0[MAXNB];
    int sps[512];
    uint2 so[CH];
    unsigned short sbs[CH];
};
struct NodeSh {
    uint2 se[HCAP];
    int hist[HB];
    int starts[HB + 1];
    int sc[HB];
};
union MegaSh {
    FillSh f;
    NodeSh n;
};   // 34816 B -> 4 blocks/CU (wave-limited 4 at 512 thr)

__device__ __forceinline__ ushort4 to_bf16x4(float4 v) {
    ushort4 o; unsigned x;
    x = __float_as_uint(v.x); x += 0x7fffu + ((x >> 16) & 1u); o.x = (unsigned short)(x >> 16);
    x = __float_as_uint(v.y); x += 0x7fffu + ((x >> 16) & 1u); o.y = (unsigned short)(x >> 16);
    x = __float_as_uint(v.z); x += 0x7fffu + ((x >> 16) & 1u); o.z = (unsigned short)(x >> 16);
    x = __float_as_uint(v.w); x += 0x7fffu + ((x >> 16) & 1u); o.w = (unsigned short)(x >> 16);
    return o;
}

__global__ __launch_bounds__(512) void mega_kernel(
        const float4* __restrict__ u4, const float* __restrict__ w,
        const int* __restrict__ row, const int* __restrict__ col,
        ushort4* __restrict__ ub, int* __restrict__ counts,
        int* __restrict__ offsets, int* __restrict__ cursor,
        uint2* __restrict__ csr, float4* __restrict__ out4,
        int N, int E, int n4, int NBH) {
    cg::grid_group grid = cg::this_grid();
    __shared__ MegaSh sh;
    const int tid = threadIdx.x;
    const int bid = blockIdx.x;
    const int nb = gridDim.x;
    const int gstride = nb * 512;
    const int gtid = bid * 512 + tid;

    // ---- P0: zero counts + u->bf16 convert ----
    if (gtid < MAXNB) counts[gtid] = 0;
    for (int i = gtid; i < n4; i += gstride)
        ub[i] = to_bf16x4(nt_load_f4(&u4[i]));
    grid.sync();

    // ---- P1: bucket histogram (LDS-local, one flush per block) ----
    for (int i = tid; i < MAXNB; i += 512) sh.f.hist[i] = 0;
    __syncthreads();
    for (int e = gtid; e < E; e += gstride)
        atomicAdd(&sh.f.hist[row[e] >> BUCKET_BITS], 1);
    __syncthreads();
    for (int b = tid; b < MAXNB; b += 512) {
        int v = sh.f.hist[b];
        if (v) atomicAdd(&counts[b], v);
    }
    grid.sync();

    // ---- P2: exclusive scan over 1024 cells (block 0, pair trick) ----
    if (bid == 0) {
        int c0 = counts[2 * tid];
        int c1 = counts[2 * tid + 1];
        int pair = c0 + c1;
        sh.f.sps[tid] = pair;
        __syncthreads();
        for (int off = 1; off < 512; off <<= 1) {
            int v = (tid >= off) ? sh.f.sps[tid - off] : 0;
            __syncthreads();
            sh.f.sps[tid] += v;
            __syncthreads();
        }
        int excl = sh.f.sps[tid] - pair;
        offsets[2 * tid] = excl;
        cursor[2 * tid] = excl;
        offsets[2 * tid + 1] = excl + c0;
        cursor[2 * tid + 1] = excl + c0;
        if (tid == 511) offsets[MAXNB] = sh.f.sps[511];
    }
    grid.sync();

    // ---- P3: chunk multisplit fill ----
    const int nChunks = (E + CH - 1) / CH;
    for (int c = bid; c < nChunks; c += nb) {
        int lo = c * CH;
        int n = min(E - lo, CH);
        __syncthreads();
        sh.f.hist[tid] = 0;
        sh.f.hist[tid + 512] = 0;
        __syncthreads();
        for (int i = tid; i < n; i += 512)
            atomicAdd(&sh.f.hist[row[lo + i] >> BUCKET_BITS], 1);
        __syncthreads();
        int c0 = sh.f.hist[2 * tid];
        int c1 = sh.f.hist[2 * tid + 1];
        int pair = c0 + c1;
        sh.f.sps[tid] = pair;
        __syncthreads();
        for (int off = 1; off < 512; off <<= 1) {
            int v = (tid >= off) ? sh.f.sps[tid - off] : 0;
            __syncthreads();
            sh.f.sps[tid] += v;
            __syncthreads();
        }
        int excl = sh.f.sps[tid] - pair;
        sh.f.sc[2 * tid] = excl;
        sh.f.sc[2 * tid + 1] = excl + c0;
        int g0 = c0 ? atomicAdd(&cursor[2 * tid], c0) : 0;
        int g1 = c1 ? atomicAdd(&cursor[2 * tid + 1], c1) : 0;
        sh.f.gb0[2 * tid] = g0;
        sh.f.gb0[2 * tid + 1] = g1;
        sh.f.hist[2 * tid] = g0;
        sh.f.hist[2 * tid + 1] = g1;
        __syncthreads();
        for (int i = tid; i < n; i += 512) {
            int r = row[lo + i];
            unsigned cc = (unsigned)col[lo + i];
            float wt = w[lo + i];
            int b = r >> BUCKET_BITS;
            uint2 p;
            p.x = ((unsigned)(r & (HB - 1)) << 25) | cc;   // rowLow:7 | col:25
            p.y = __float_as_uint(wt);
            int d = atomicAdd(&sh.f.hist[b], 1);
            int pos = sh.f.sc[b] + (d - sh.f.gb0[b]);
            sh.f.so[pos] = p;
            sh.f.sbs[pos] = (unsigned short)b;
        }
        __syncthreads();
        for (int i = tid; i < n; i += 512) {
            int b = sh.f.sbs[i];
            csr[sh.f.gb0[b] + (i - sh.f.sc[b])] = sh.f.so[i];
        }
    }
    grid.sync();

    // ---- P4: per-segment counting sort + register accumulation ----
    for (int b = bid; b < NBH; b += nb) {
        int start = offsets[b];
        int end = offsets[b + 1];
        int cnt = end - start;
        __syncthreads();
        if (tid < HB) sh.n.hist[tid] = 0;
        __syncthreads();
        if (cnt <= HCAP) {
            for (int i = start + tid; i < end; i += 512)
                atomicAdd(&sh.n.hist[nt_load_u2(&csr[i]).x >> 25], 1);
            __syncthreads();
            int myc = (tid < HB) ? sh.n.hist[tid] : 0;
            if (tid < HB) sh.n.sc[tid] = myc;
            __syncthreads();
            for (int off = 1; off < HB; off <<= 1) {
                int v = (tid < HB && tid >= off) ? sh.n.sc[tid - off] : 0;
                __syncthreads();
                if (tid < HB) sh.n.sc[tid] += v;
                __syncthreads();
            }
            if (tid < HB) {
                int excl = sh.n.sc[tid] - myc;
                sh.n.starts[tid] = excl;
                sh.n.hist[tid] = excl;
            }
            if (tid == HB - 1) sh.n.starts[HB] = sh.n.sc[HB - 1];
            __syncthreads();
            for (int i = start + tid; i < end; i += 512) {
                uint2 p = nt_load_u2(&csr[i]);
                int pos = atomicAdd(&sh.n.hist[p.x >> 25], 1);
                sh.n.se[pos] = p;
            }
            __syncthreads();
            int wave = tid >> 6;
            int lane = tid & 63;
            int f4 = lane & 7;
            int slot = lane >> 3;
            for (int node = wave; node < HB; node += 8) {
                int s0 = sh.n.starts[node];
                int s1 = sh.n.starts[node + 1];
                float4 acc = make_float4(0.f, 0.f, 0.f, 0.f);
                float ws_ = 0.f;
                for (int i = s0 + slot; i < s1; i += 8) {
                    uint2 p = sh.n.se[i];
                    int cc = (int)(p.x & 0x01FFFFFFu);
                    float wt = __uint_as_float(p.y);
                    ushort4 us = ub[(size_t)cc * 8 + f4];
                    acc.x += wt * __uint_as_float((unsigned)us.x << 16);
                    acc.y += wt * __uint_as_float((unsigned)us.y << 16);
                    acc.z += wt * __uint_as_float((unsigned)us.z << 16);
                    acc.w += wt * __uint_as_float((unsigned)us.w << 16);
                    ws_ += wt;
                }
#pragma unroll
                for (int m = 8; m < 64; m <<= 1) {
                    acc.x += __shfl_xor(acc.x, m, 64);
                    acc.y += __shfl_xor(acc.y, m, 64);
                    acc.z += __shfl_xor(acc.z, m, 64);
                    acc.w += __shfl_xor(acc.w, m, 64);
                    ws_   += __shfl_xor(ws_,   m, 64);
                }
                int glob = b * HB + node;
                if (slot == 0 && glob < N) {
                    float4 ur = nt_load_f4(&u4[(size_t)glob * 8 + f4]);
                    float4 o;
                    o.x = acc.x - ws_ * ur.x;
                    o.y = acc.y - ws_ * ur.y;
                    o.z = acc.z - ws_ * ur.z;
                    o.w = acc.w - ws_ * ur.w;
                    nt_store_f4(&out4[(size_t)glob * 8 + f4], o);
                }
            }
        } else {
            // oversized segment: LDS f32 tile (16 KB, overlays se)
            float* tile = (float*)sh.n.se;
            float* wsumf = (float*)sh.n.sc;
            for (int i = tid; i < HB * NFEAT; i += 512) tile[i] = 0.f;
            if (tid < HB) wsumf[tid] = 0.f;
            __syncthreads();
            int f4 = tid & 7;
            for (int i = start + (tid >> 3); i < end; i += 64) {
                uint2 p = nt_load_u2(&csr[i]);
                int rl = (int)(p.x >> 25);
                int cc = (int)(p.x & 0x01FFFFFFu);
                float wt = __uint_as_float(p.y);
                ushort4 us = ub[(size_t)cc * 8 + f4];
                float* t = &tile[rl * NFEAT + f4 * 4];
                atomicAdd(t + 0, wt * __uint_as_float((unsigned)us.x << 16));
                atomicAdd(t + 1, wt * __uint_as_float((unsigned)us.y << 16));
                atomicAdd(t + 2, wt * __uint_as_float((unsigned)us.z << 16));
                atomicAdd(t + 3, wt * __uint_as_float((unsigned)us.w << 16));
                if (f4 == 0) atomicAdd(&wsumf[rl], wt);
            }
            __syncthreads();
#pragma unroll
            for (int pass = 0; pass < 2; ++pass) {
                int idx = pass * 512 + tid;
                int node = idx >> 3;
                int ff = idx & 7;
                int glob = b * HB + node;
                if (glob < N) {
                    float4 ur = nt_load_f4(&u4[(size_t)glob * 8 + ff]);
                    float ws_ = wsumf[node];
                    const float* t = &tile[node * NFEAT + ff * 4];
                    float4 o;
                    o.x = t[0] - ws_ * ur.x;
                    o.y = t[1] - ws_ * ur.y;
                    o.z = t[2] - ws_ * ur.z;
                    o.w = t[3] - ws_ * ur.w;
                    nt_store_f4(&out4[(size_t)glob * 8 + ff], o);
                }
            }
        }
    }
}

// ---------------- fallback (atomic path, ws too small / coop failure) --------

__global__ __launch_bounds__(256) void zero_out_kernel(float* __restrict__ out, int n) {
    int i = blockIdx.x * blockDim.x + threadIdx.x;
    if (i < n) out[i] = 0.0f;
}

__global__ __launch_bounds__(256) void scatter_lap_kernel(const float4* __restrict__ u4,
                                                          const float* __restrict__ w,
                                                          const int* __restrict__ row,
                                                          const int* __restrict__ col,
                                                          float* __restrict__ out, int n_edges) {
    int tid = blockIdx.x * blockDim.x + threadIdx.x;
    int e = tid >> 3;
    int f4 = tid & 7;
    if (e >= n_edges) return;
    int r = row[e];
    int c = col[e];
    float wt = w[e];
    float4 uc = u4[(size_t)c * 8 + f4];
    float4 ur = u4[(size_t)r * 8 + f4];
    float* o = out + (size_t)r * NFEAT + f4 * 4;
    atomicAdd(o + 0, wt * (uc.x - ur.x));
    atomicAdd(o + 1, wt * (uc.y - ur.y));
    atomicAdd(o + 2, wt * (uc.z - ur.z));
    atomicAdd(o + 3, wt * (uc.w - ur.w));
}

extern "C" void kernel_launch(void* const* d_in, const int* in_sizes, int n_in,
                              void* d_out, int out_size, void* d_ws, size_t ws_size,
                              hipStream_t stream) {
    const float* u = (const float*)d_in[0];
    const float* w = (const float*)d_in[1];
    const int* ei = (const int*)d_in[2];  // [2, E] int32
    float* out = (float*)d_out;

    const int E = in_sizes[1];
    const int N = out_size / NFEAT;
    const int* row = ei;
    const int* col = ei + E;

    const int NBH = (N + HB - 1) >> BUCKET_BITS;

    // workspace layout (256-B aligned)
    const size_t countsOff = 0;
    const size_t countsBytes = ((size_t)MAXNB * 4 + 255) & ~(size_t)255;
    const size_t offsetsOff = countsOff + countsBytes;
    const size_t offsetsBytes = ((size_t)(MAXNB + 1) * 4 + 255) & ~(size_t)255;
    const size_t cursorOff = offsetsOff + offsetsBytes;
    const size_t cursorBytes = countsBytes;
    const size_t csrOff = cursorOff + cursorBytes;
    const size_t csrBytes = ((size_t)E * 8 + 255) & ~(size_t)255;
    const size_t ubOff = csrOff + csrBytes;
    const size_t ubBytes = ((size_t)N * NFEAT * 2 + 255) & ~(size_t)255;
    const size_t totalWs = ubOff + ubBytes;

    bool mega_ok = (ws_size >= totalWs) && (NBH <= MAXNB - 1);

    int G = 0;
    if (mega_ok) {
        int occ = 0, nCU = 0;
        hipError_t e1 = hipOccupancyMaxActiveBlocksPerMultiprocessor(&occ, mega_kernel, 512, 0);
        hipDeviceProp_t prop;
        int dev = 0;
        (void)hipGetDevice(&dev);
        hipError_t e2 = hipGetDeviceProperties(&prop, dev);
        nCU = (e2 == hipSuccess) ? prop.multiProcessorCount : 256;
        if (e1 != hipSuccess || occ < 1) occ = 1;
        G = occ * nCU;
        if (G < 2) G = 2;               // counts-zeroing needs >= 1024 threads
        if (G > 2048) G = 2048;
        mega_ok = true;
    }

    if (mega_ok) {
        char* ws = (char*)d_ws;
        const float4* u4p = (const float4*)u;
        const float* wp = w;
        const int* rowp = row;
        const int* colp = col;
        ushort4* ubp = (ushort4*)(ws + ubOff);
        int* countsp = (int*)(ws + countsOff);
        int* offsetsp = (int*)(ws + offsetsOff);
        int* cursorp = (int*)(ws + cursorOff);
        uint2* csrp = (uint2*)(ws + csrOff);
        float4* outp = (float4*)out;
        int Nv = N, Ev = E, n4v = N * (NFEAT / 4), NBHv = NBH;
        void* args[] = {
            (void*)&u4p, (void*)&wp, (void*)&rowp, (void*)&colp,
            (void*)&ubp, (void*)&countsp, (void*)&offsetsp, (void*)&cursorp,
            (void*)&csrp, (void*)&outp, (void*)&Nv, (void*)&Ev, (void*)&n4v, (void*)&NBHv
        };
        hipError_t err = hipLaunchCooperativeKernel((void*)mega_kernel, dim3(G), dim3(512),
                                                    args, 0, stream);
        if (err == hipSuccess) return;
        // else fall through to atomic fallback (deterministic per-device)
    }

    // fallback: zero + atomic scatter
    zero_out_kernel<<<(out_size + 255) / 256, 256, 0, stream>>>(out, out_size);
    long long threads_total = (long long)E * 8;
    scatter_lap_kernel<<<(unsigned)((threads_total + 255) / 256), 256, 0, stream>>>(
        (const float4*)u, w, row, col, out, E);
}

// Round 14
// 183.232 us; speedup vs baseline: 2.8136x; 2.8136x over previous
//
#include <hip/hip_runtime.h>

// DiffusionMLS: out[row[e]] += w[e]*(u[col[e]] - u[row[e]]), F=32 fp32.
// Round 14: r12 pipeline compressed to 4 dispatches, zero global-atomic hist.
// (r13's cooperative mega-kernel regressed 2.7x: grid.sync across 8 XCDs
// ~100us each. Launch boundaries are cheaper than software grid barriers.)
//  1) conv+hist: u->bf16 convert blocks + 256 hist blocks writing PRIVATE
//     1024-cell histograms (plain stores -> no memset, no atomics).
//  2) scan: sum 256 partials/cell (coalesced) + pair-scan -> offsets/cursor.
//  3) fill: chunk multisplit (r12).  4) node: per-segment sort+acc (r12).

#define NFEAT 32
#define BUCKET_BITS 7
#define HB 128               // nodes per segment; rowLow fits 7 bits
#define MAXNB 1024           // scan/fill cell count (NBH <= 1023)
#define CH 2048              // edges per fill chunk
#define HCAP 2560            // node-phase LDS staging cap
#define HBLK 256             // histogram partial blocks

typedef float nfloat4 __attribute__((ext_vector_type(4)));
typedef unsigned int nuint2 __attribute__((ext_vector_type(2)));

__device__ __forceinline__ float4 nt_load_f4(const float4* p) {
    nfloat4 v = __builtin_nontemporal_load((const nfloat4*)p);
    return make_float4(v.x, v.y, v.z, v.w);
}
__device__ __forceinline__ void nt_store_f4(float4* p, float4 v) {
    nfloat4 t = {v.x, v.y, v.z, v.w};
    __builtin_nontemporal_store(t, (nfloat4*)p);
}
__device__ __forceinline__ uint2 nt_load_u2(const uint2* p) {
    nuint2 v = __builtin_nontemporal_load((const nuint2*)p);
    uint2 r; r.x = v.x; r.y = v.y; return r;
}

// ---- dispatch 1: convert blocks [0,convBlocks) + hist blocks [convBlocks,+HBLK)
__global__ __launch_bounds__(512) void conv_hist_kernel(const float4* __restrict__ u4,
                                                        ushort4* __restrict__ ub, int n4,
                                                        const int* __restrict__ row,
                                                        int* __restrict__ hist_part,
                                                        int E, int convBlocks) {
    __shared__ int h[MAXNB];
    if ((int)blockIdx.x < convBlocks) {
        int i = blockIdx.x * 512 + threadIdx.x;
        if (i >= n4) return;
        float4 v = nt_load_f4(&u4[i]);
        ushort4 o;
        unsigned x;
        x = __float_as_uint(v.x); x += 0x7fffu + ((x >> 16) & 1u); o.x = (unsigned short)(x >> 16);
        x = __float_as_uint(v.y); x += 0x7fffu + ((x >> 16) & 1u); o.y = (unsigned short)(x >> 16);
        x = __float_as_uint(v.z); x += 0x7fffu + ((x >> 16) & 1u); o.z = (unsigned short)(x >> 16);
        x = __float_as_uint(v.w); x += 0x7fffu + ((x >> 16) & 1u); o.w = (unsigned short)(x >> 16);
        ub[i] = o;
    } else {
        int hb = blockIdx.x - convBlocks;
        for (int i = threadIdx.x; i < MAXNB; i += 512) h[i] = 0;
        __syncthreads();
        int stride = HBLK * 512;
        for (int e = hb * 512 + threadIdx.x; e < E; e += stride)
            atomicAdd(&h[__builtin_nontemporal_load(&row[e]) >> BUCKET_BITS], 1);
        __syncthreads();
        int* dst = hist_part + (size_t)hb * MAXNB;
        for (int i = threadIdx.x; i < MAXNB; i += 512) dst[i] = h[i];   // plain store
    }
}

// ---- dispatch 2: sum partials + pair-scan -> offsets & cursor ----
__global__ __launch_bounds__(512) void scan_offsets_kernel(const int* __restrict__ hist_part,
                                                           int* __restrict__ offsets,
                                                           int* __restrict__ cursor) {
    __shared__ int sps[512];
    int t = threadIdx.x;
    int c0 = 0, c1 = 0;
    for (int p = 0; p < HBLK; ++p) {
        const int* src = hist_part + (size_t)p * MAXNB;
        c0 += src[2 * t];
        c1 += src[2 * t + 1];
    }
    int pair = c0 + c1;
    sps[t] = pair;
    __syncthreads();
    for (int off = 1; off < 512; off <<= 1) {
        int v = (t >= off) ? sps[t - off] : 0;
        __syncthreads();
        sps[t] += v;
        __syncthreads();
    }
    int excl = sps[t] - pair;
    offsets[2 * t] = excl;
    cursor[2 * t] = excl;
    offsets[2 * t + 1] = excl + c0;
    cursor[2 * t + 1] = excl + c0;
    if (t == 511) offsets[MAXNB] = sps[511];   // = E
}

// ---- dispatch 3: chunk multisplit fill (r12) ----
__global__ __launch_bounds__(512) void fill_sort_kernel(const int* __restrict__ row,
                                                        const int* __restrict__ col,
                                                        const float* __restrict__ w,
                                                        int* __restrict__ cursor,
                                                        uint2* __restrict__ csr,
                                                        int E) {
    __shared__ int hist[MAXNB];           // 4K
    __shared__ int sc[MAXNB];             // 4K
    __shared__ int gb0[MAXNB];            // 4K
    __shared__ int sps[512];              // 2K
    __shared__ uint2 so[CH];              // 16K
    __shared__ unsigned short sbs[CH];    // 4K

    int tid = threadIdx.x;
    int lo = blockIdx.x * CH;
    int n = min(E - lo, CH);

    hist[tid] = 0;
    hist[tid + 512] = 0;
    __syncthreads();

    for (int i = tid; i < n; i += 512)
        atomicAdd(&hist[__builtin_nontemporal_load(&row[lo + i]) >> BUCKET_BITS], 1);
    __syncthreads();

    int c0 = hist[2 * tid];
    int c1 = hist[2 * tid + 1];
    int pair = c0 + c1;
    sps[tid] = pair;
    __syncthreads();
    for (int off = 1; off < 512; off <<= 1) {
        int v = (tid >= off) ? sps[tid - off] : 0;
        __syncthreads();
        sps[tid] += v;
        __syncthreads();
    }
    int excl = sps[tid] - pair;
    sc[2 * tid] = excl;
    sc[2 * tid + 1] = excl + c0;

    int g0 = c0 ? atomicAdd(&cursor[2 * tid], c0) : 0;
    int g1 = c1 ? atomicAdd(&cursor[2 * tid + 1], c1) : 0;
    gb0[2 * tid] = g0;
    gb0[2 * tid + 1] = g1;
    hist[2 * tid] = g0;
    hist[2 * tid + 1] = g1;
    __syncthreads();

    for (int i = tid; i < n; i += 512) {
        int r = __builtin_nontemporal_load(&row[lo + i]);
        unsigned c = (unsigned)__builtin_nontemporal_load(&col[lo + i]);
        float wt = __builtin_nontemporal_load(&w[lo + i]);
        int b = r >> BUCKET_BITS;
        uint2 p;
        p.x = ((unsigned)(r & (HB - 1)) << 25) | c;   // rowLow:7 | col:25
        p.y = __float_as_uint(wt);
        int d = atomicAdd(&hist[b], 1);
        int pos = sc[b] + (d - gb0[b]);
        so[pos] = p;
        sbs[pos] = (unsigned short)b;
    }
    __syncthreads();

    for (int i = tid; i < n; i += 512) {
        int b = sbs[i];
        csr[gb0[b] + (i - sc[b])] = so[i];
    }
}

// ---- dispatch 4: per-segment counting sort + register accumulation (r12) ----
__global__ __launch_bounds__(512) void node_half_kernel(const ushort4* __restrict__ ub,
                                                        const float4* __restrict__ u4,
                                                        const int* __restrict__ offsets,
                                                        const uint2* __restrict__ csr,
                                                        float4* __restrict__ out4, int N) {
    __shared__ uint2 se[HCAP];          // 20.5 KB (fallback: f32 tile 16 KB)
    __shared__ int hist[HB];
    __shared__ int starts[HB + 1];
    __shared__ int sc[HB];

    int b = blockIdx.x;
    int tid = threadIdx.x;
    int start = offsets[b];
    int end = offsets[b + 1];
    int cnt = end - start;

    if (tid < HB) hist[tid] = 0;
    __syncthreads();

    if (cnt <= HCAP) {
        for (int i = start + tid; i < end; i += 512)
            atomicAdd(&hist[nt_load_u2(&csr[i]).x >> 25], 1);
        __syncthreads();
        int myc = (tid < HB) ? hist[tid] : 0;
        if (tid < HB) sc[tid] = myc;
        __syncthreads();
        for (int off = 1; off < HB; off <<= 1) {
            int v = (tid < HB && tid >= off) ? sc[tid - off] : 0;
            __syncthreads();
            if (tid < HB) sc[tid] += v;
            __syncthreads();
        }
        if (tid < HB) {
            int excl = sc[tid] - myc;
            starts[tid] = excl;
            hist[tid] = excl;       // cursor
        }
        if (tid == HB - 1) starts[HB] = sc[HB - 1];
        __syncthreads();
        for (int i = start + tid; i < end; i += 512) {
            uint2 p = nt_load_u2(&csr[i]);
            int pos = atomicAdd(&hist[p.x >> 25], 1);
            se[pos] = p;
        }
        __syncthreads();
        int wave = tid >> 6;
        int lane = tid & 63;
        int f4 = lane & 7;
        int slot = lane >> 3;
        for (int node = wave; node < HB; node += 8) {
            int s0 = starts[node];
            int s1 = starts[node + 1];
            float4 acc = make_float4(0.f, 0.f, 0.f, 0.f);
            float ws_ = 0.f;
            for (int i = s0 + slot; i < s1; i += 8) {
                uint2 p = se[i];
                int c = (int)(p.x & 0x01FFFFFFu);
                float wt = __uint_as_float(p.y);
                ushort4 us = ub[(size_t)c * 8 + f4];
                acc.x += wt * __uint_as_float((unsigned)us.x << 16);
                acc.y += wt * __uint_as_float((unsigned)us.y << 16);
                acc.z += wt * __uint_as_float((unsigned)us.z << 16);
                acc.w += wt * __uint_as_float((unsigned)us.w << 16);
                ws_ += wt;
            }
#pragma unroll
            for (int m = 8; m < 64; m <<= 1) {
                acc.x += __shfl_xor(acc.x, m, 64);
                acc.y += __shfl_xor(acc.y, m, 64);
                acc.z += __shfl_xor(acc.z, m, 64);
                acc.w += __shfl_xor(acc.w, m, 64);
                ws_   += __shfl_xor(ws_,   m, 64);
            }
            int glob = b * HB + node;
            if (slot == 0 && glob < N) {
                float4 ur = nt_load_f4(&u4[(size_t)glob * 8 + f4]);
                float4 o;
                o.x = acc.x - ws_ * ur.x;
                o.y = acc.y - ws_ * ur.y;
                o.z = acc.z - ws_ * ur.z;
                o.w = acc.w - ws_ * ur.w;
                nt_store_f4(&out4[(size_t)glob * 8 + f4], o);
            }
        }
    } else {
        float* tile = (float*)se;   // HB*32 floats
        float* wsumf = (float*)sc;
        for (int i = tid; i < HB * NFEAT; i += 512) tile[i] = 0.f;
        if (tid < HB) wsumf[tid] = 0.f;
        __syncthreads();
        int f4 = tid & 7;
        for (int i = start + (tid >> 3); i < end; i += 64) {
            uint2 p = nt_load_u2(&csr[i]);
            int rl = (int)(p.x >> 25);
            int c = (int)(p.x & 0x01FFFFFFu);
            float wt = __uint_as_float(p.y);
            ushort4 us = ub[(size_t)c * 8 + f4];
            float* t = &tile[rl * NFEAT + f4 * 4];
            atomicAdd(t + 0, wt * __uint_as_float((unsigned)us.x << 16));
            atomicAdd(t + 1, wt * __uint_as_float((unsigned)us.y << 16));
            atomicAdd(t + 2, wt * __uint_as_float((unsigned)us.z << 16));
            atomicAdd(t + 3, wt * __uint_as_float((unsigned)us.w << 16));
            if (f4 == 0) atomicAdd(&wsumf[rl], wt);
        }
        __syncthreads();
#pragma unroll
        for (int pass = 0; pass < 2; ++pass) {
            int idx = pass * 512 + tid;
            int node = idx >> 3;
            int ff = idx & 7;
            int glob = b * HB + node;
            if (glob < N) {
                float4 ur = nt_load_f4(&u4[(size_t)glob * 8 + ff]);
                float ws_ = wsumf[node];
                const float* t = &tile[node * NFEAT + ff * 4];
                float4 o;
                o.x = t[0] - ws_ * ur.x;
                o.y = t[1] - ws_ * ur.y;
                o.z = t[2] - ws_ * ur.z;
                o.w = t[3] - ws_ * ur.w;
                nt_store_f4(&out4[(size_t)glob * 8 + ff], o);
            }
        }
    }
}

// ---------------- fallback (atomic path) ----------------

__global__ __launch_bounds__(256) void zero_out_kernel(float* __restrict__ out, int n) {
    int i = blockIdx.x * blockDim.x + threadIdx.x;
    if (i < n) out[i] = 0.0f;
}

__global__ __launch_bounds__(256) void scatter_lap_kernel(const float4* __restrict__ u4,
                                                          const float* __restrict__ w,
                                                          const int* __restrict__ row,
                                                          const int* __restrict__ col,
                                                          float* __restrict__ out, int n_edges) {
    int tid = blockIdx.x * blockDim.x + threadIdx.x;
    int e = tid >> 3;
    int f4 = tid & 7;
    if (e >= n_edges) return;
    int r = row[e];
    int c = col[e];
    float wt = w[e];
    float4 uc = u4[(size_t)c * 8 + f4];
    float4 ur = u4[(size_t)r * 8 + f4];
    float* o = out + (size_t)r * NFEAT + f4 * 4;
    atomicAdd(o + 0, wt * (uc.x - ur.x));
    atomicAdd(o + 1, wt * (uc.y - ur.y));
    atomicAdd(o + 2, wt * (uc.z - ur.z));
    atomicAdd(o + 3, wt * (uc.w - ur.w));
}

extern "C" void kernel_launch(void* const* d_in, const int* in_sizes, int n_in,
                              void* d_out, int out_size, void* d_ws, size_t ws_size,
                              hipStream_t stream) {
    const float* u = (const float*)d_in[0];
    const float* w = (const float*)d_in[1];
    const int* ei = (const int*)d_in[2];  // [2, E] int32
    float* out = (float*)d_out;

    const int E = in_sizes[1];
    const int N = out_size / NFEAT;
    const int* row = ei;
    const int* col = ei + E;

    const int NBH = (N + HB - 1) >> BUCKET_BITS;

    // workspace layout (256-B aligned)
    const size_t histPartOff = 0;
    const size_t histPartBytes = ((size_t)HBLK * MAXNB * 4 + 255) & ~(size_t)255;  // 1 MB
    const size_t offsetsOff = histPartOff + histPartBytes;
    const size_t offsetsBytes = ((size_t)(MAXNB + 1) * 4 + 255) & ~(size_t)255;
    const size_t cursorOff = offsetsOff + offsetsBytes;
    const size_t cursorBytes = ((size_t)MAXNB * 4 + 255) & ~(size_t)255;
    const size_t csrOff = cursorOff + cursorBytes;
    const size_t csrBytes = ((size_t)E * 8 + 255) & ~(size_t)255;
    const size_t ubOff = csrOff + csrBytes;
    const size_t ubBytes = ((size_t)N * NFEAT * 2 + 255) & ~(size_t)255;
    const size_t totalWs = ubOff + ubBytes;

    if (ws_size < totalWs || NBH > MAXNB - 1) {
        zero_out_kernel<<<(out_size + 255) / 256, 256, 0, stream>>>(out, out_size);
        long long threads_total = (long long)E * 8;
        scatter_lap_kernel<<<(unsigned)((threads_total + 255) / 256), 256, 0, stream>>>(
            (const float4*)u, w, row, col, out, E);
        return;
    }

    char* ws = (char*)d_ws;
    int* hist_part = (int*)(ws + histPartOff);
    int* offsets = (int*)(ws + offsetsOff);
    int* cursor = (int*)(ws + cursorOff);
    uint2* csr = (uint2*)(ws + csrOff);
    ushort4* ub = (ushort4*)(ws + ubOff);

    // 1: convert + private histograms (no memset, no global atomics)
    int n4 = N * (NFEAT / 4);
    int convBlocks = (n4 + 511) / 512;
    conv_hist_kernel<<<convBlocks + HBLK, 512, 0, stream>>>((const float4*)u, ub, n4,
                                                            row, hist_part, E, convBlocks);

    // 2: sum partials + pair scan -> offsets + cursor
    scan_offsets_kernel<<<1, 512, 0, stream>>>(hist_part, offsets, cursor);

    // 3: chunk multisplit fill
    const int nChunks = (E + CH - 1) / CH;
    fill_sort_kernel<<<nChunks, 512, 0, stream>>>(row, col, w, cursor, csr, E);

    // 4: one block per half-bucket segment
    node_half_kernel<<<NBH, 512, 0, stream>>>(ub, (const float4*)u, offsets, csr,
                                              (float4*)out, N);
}